// Round 1
// baseline (300.046 us; speedup 1.0000x reference)
//
#include <hip/hip_runtime.h>
#include <math.h>

// Shapes (fixed by the reference)
#define BB   16
#define CC   16      // IN_CHAN
#define LL   4096
#define OUTC 64
#define KS   7

typedef float vfloat2 __attribute__((ext_vector_type(2)));
typedef float vfloat4 __attribute__((ext_vector_type(4)));

// ---------------------------------------------------------------------------
// Pre-pass: transpose x (B,L,C) -> xT (B,C,L) so bilinear gathers are
// contiguous along l (the gather axis). 8 MB of traffic ~= 1.5 us.
// ---------------------------------------------------------------------------
__global__ __launch_bounds__(256) void transpose_kernel(
    const float* __restrict__ x, float* __restrict__ xT)
{
    __shared__ float tile[64 * 17];  // 64 l x 16 c, stride 17 (conflict-free)
    const int b   = blockIdx.x >> 6;
    const int l0  = (blockIdx.x & 63) * 64;
    const int tid = threadIdx.x;
    {
        const int lo = tid >> 2, cq = (tid & 3) * 4;
        float4 v = *(const float4*)(x + ((size_t)(b * LL + l0 + lo)) * CC + cq);
        tile[lo * 17 + cq + 0] = v.x;
        tile[lo * 17 + cq + 1] = v.y;
        tile[lo * 17 + cq + 2] = v.z;
        tile[lo * 17 + cq + 3] = v.w;
    }
    __syncthreads();
    {
        const int c = tid >> 4, li = (tid & 15) * 4;
        float4 v;
        v.x = tile[(li + 0) * 17 + c];
        v.y = tile[(li + 1) * 17 + c];
        v.z = tile[(li + 2) * 17 + c];
        v.w = tile[(li + 3) * 17 + c];
        *(float4*)(xT + ((size_t)(b * CC + c)) * LL + l0 + li) = v;
    }
}

// ---------------------------------------------------------------------------
// Main kernel. grid = 16 b x 128 l-tiles (2048 blocks -> 8 blocks/CU).
// Thread = (l, channel-pair): tid>>3 = l offset (32), tid&7 = c-pair (8).
// USE_XT: gather from transposed buffer (fast path). Fallback gathers from x
// directly if the workspace is too small.
// ---------------------------------------------------------------------------
template <bool USE_XT>
__global__ __launch_bounds__(256, 6) void deform_conv_kernel(
    const float* __restrict__ x,    // (B,1,L,C)
    const float* __restrict__ xT,   // (B,C,L) or nullptr
    const float* __restrict__ p_w, const float* __restrict__ p_b,
    const float* __restrict__ m_w, const float* __restrict__ m_b,
    const float* __restrict__ c_w, const float* __restrict__ c_b,
    float* __restrict__ out)        // (B,64,L,C)
{
    __shared__ float cw_lds[OUTC * 8];  // [o][0..6]=w, [7]=bias
    __shared__ float pw_lds[KS * 4];    // [k][0..2]=w, [3]=bias
    __shared__ float mw_lds[KS * 4];

    const int tid = threadIdx.x;

    for (int i = tid; i < OUTC * 8; i += 256) {
        int o = i >> 3, j = i & 7;
        cw_lds[i] = (j < 7) ? c_w[o * 7 + j] : c_b[o];
    }
    if (tid < KS * 4) {
        int k = tid >> 2, j = tid & 3;
        pw_lds[tid] = (j < 3) ? p_w[k * 3 + j] : p_b[k];
        mw_lds[tid] = (j < 3) ? m_w[k * 3 + j] : m_b[k];
    }
    __syncthreads();

    const int b     = blockIdx.x >> 7;   // 16 batches
    const int ltile = blockIdx.x & 127;  // 128 tiles of 32 positions
    const int l     = ltile * 32 + (tid >> 3);
    const int c0    = (tid & 7) * 2;     // channel pair

    const float* xb = x + (size_t)b * (LL * CC);

    // 3-tap conv inputs (zero pad at boundaries); coalesced float2 loads
    float s_m1[2] = {0.f, 0.f};
    float s_p1[2] = {0.f, 0.f};
    float s_0[2];
    {
        float2 v0 = *(const float2*)(xb + l * CC + c0);
        s_0[0] = v0.x; s_0[1] = v0.y;
        if (l > 0) {
            float2 vm = *(const float2*)(xb + (l - 1) * CC + c0);
            s_m1[0] = vm.x; s_m1[1] = vm.y;
        }
        if (l < LL - 1) {
            float2 vp = *(const float2*)(xb + (l + 1) * CC + c0);
            s_p1[0] = vp.x; s_p1[1] = vp.y;
        }
    }

    // x_off[c][k]: bilinear-gathered, masked samples
    float xoff[2][KS];
    const float pl = (float)(l + 1);
    const float* xt0 = USE_XT ? (xT + (size_t)(b * CC + c0) * LL) : nullptr;
    #pragma unroll
    for (int k = 0; k < KS; ++k) {
        float4 pw = *(const float4*)(pw_lds + k * 4);  // x,y,z = taps, w = bias
        float4 mw = *(const float4*)(mw_lds + k * 4);
        const float pn = (float)(k - 3);
        #pragma unroll
        for (int c = 0; c < 2; ++c) {
            float off  = pw.w + pw.x * s_m1[c] + pw.y * s_0[c] + pw.z * s_p1[c];
            float mact = mw.w + mw.x * s_m1[c] + mw.y * s_0[c] + mw.z * s_p1[c];
            float mm   = 1.f / (1.f + __expf(-mact));   // sigmoid

            float p    = pl + pn + off;
            float qltf = fminf(fmaxf(floorf(p), 0.f), (float)(LL - 1));
            float qrbf = fminf(qltf + 1.f, (float)(LL - 1));
            float pc   = fminf(fmaxf(p, 0.f), (float)(LL - 1));
            float glt  = 1.f + (qltf - pc);
            float grb  = 1.f - (qrbf - pc);

            float xlt, xrb;
            if (USE_XT) {
                // Contiguous along l: neighbors are adjacent floats.
                // Load at min(ilt, LL-2); covers the ilt==LL-1 clamp case
                // (there q_lt==q_rb==LL-1 -> both samples are x[LL-1]).
                int iload = (int)fminf(qltf, (float)(LL - 2));
                const float* pr = xt0 + (size_t)c * LL + iload;
                float va = pr[0];
                float vb = pr[1];
                xlt = (qltf >= (float)(LL - 1)) ? vb : va;
                xrb = vb;
            } else {
                int ilt = (int)qltf;
                int irb = (int)qrbf;
                xlt = xb[ilt * CC + c0 + c];
                xrb = xb[irb * CC + c0 + c];
            }
            xoff[c][k] = (glt * xlt + grb * xrb) * mm;
        }
    }

    // 7 -> 64 output-channel dot; nontemporal float2 stores (write-streaming)
    float* outp = out + ((size_t)(b * OUTC) * LL + l) * CC + c0;
    #pragma unroll 4
    for (int o = 0; o < OUTC; ++o) {
        float4 w0 = *(const float4*)(cw_lds + o * 8);      // k=0..3
        float4 w1 = *(const float4*)(cw_lds + o * 8 + 4);  // k=4..6, bias
        vfloat2 res;
        #pragma unroll
        for (int c = 0; c < 2; ++c) {
            float a = w1.w;
            a += w0.x * xoff[c][0];
            a += w0.y * xoff[c][1];
            a += w0.z * xoff[c][2];
            a += w0.w * xoff[c][3];
            a += w1.x * xoff[c][4];
            a += w1.y * xoff[c][5];
            a += w1.z * xoff[c][6];
            res[c] = a;
        }
        __builtin_nontemporal_store(res, (vfloat2*)(outp + (size_t)o * (LL * CC)));
    }
}

extern "C" void kernel_launch(void* const* d_in, const int* in_sizes, int n_in,
                              void* d_out, int out_size, void* d_ws, size_t ws_size,
                              hipStream_t stream) {
    const float* x   = (const float*)d_in[0];
    const float* p_w = (const float*)d_in[1];
    const float* p_b = (const float*)d_in[2];
    const float* m_w = (const float*)d_in[3];
    const float* m_b = (const float*)d_in[4];
    const float* c_w = (const float*)d_in[5];
    const float* c_b = (const float*)d_in[6];
    float* out = (float*)d_out;

    const size_t xt_bytes = (size_t)BB * CC * LL * sizeof(float);  // 4 MB
    if (d_ws != nullptr && ws_size >= xt_bytes) {
        float* xT = (float*)d_ws;
        transpose_kernel<<<dim3(BB * 64), dim3(256), 0, stream>>>(x, xT);
        deform_conv_kernel<true><<<dim3(BB * 128), dim3(256), 0, stream>>>(
            x, xT, p_w, p_b, m_w, m_b, c_w, c_b, out);
    } else {
        deform_conv_kernel<false><<<dim3(BB * 128), dim3(256), 0, stream>>>(
            x, nullptr, p_w, p_b, m_w, m_b, c_w, c_b, out);
    }
}

// Round 2
// 294.833 us; speedup vs baseline: 1.0177x; 1.0177x over previous
//
#include <hip/hip_runtime.h>
#include <math.h>

// Shapes (fixed by the reference)
#define BB   16
#define CC   16      // IN_CHAN
#define LL   4096
#define OUTC 64
#define KS   7

typedef float vfloat4 __attribute__((ext_vector_type(4)));

// ---------------------------------------------------------------------------
// Pre-pass: transpose x (B,L,C) -> xT (B,C,L) so bilinear gathers are
// contiguous along l (the gather axis).
// ---------------------------------------------------------------------------
__global__ __launch_bounds__(256) void transpose_kernel(
    const float* __restrict__ x, float* __restrict__ xT)
{
    __shared__ float tile[64 * 17];  // 64 l x 16 c, stride 17 (conflict-free)
    const int b   = blockIdx.x >> 6;
    const int l0  = (blockIdx.x & 63) * 64;
    const int tid = threadIdx.x;
    {
        const int lo = tid >> 2, cq = (tid & 3) * 4;
        float4 v = *(const float4*)(x + ((size_t)(b * LL + l0 + lo)) * CC + cq);
        tile[lo * 17 + cq + 0] = v.x;
        tile[lo * 17 + cq + 1] = v.y;
        tile[lo * 17 + cq + 2] = v.z;
        tile[lo * 17 + cq + 3] = v.w;
    }
    __syncthreads();
    {
        const int c = tid >> 4, li = (tid & 15) * 4;
        float4 v;
        v.x = tile[(li + 0) * 17 + c];
        v.y = tile[(li + 1) * 17 + c];
        v.z = tile[(li + 2) * 17 + c];
        v.w = tile[(li + 3) * 17 + c];
        *(float4*)(xT + ((size_t)(b * CC + c)) * LL + l0 + li) = v;
    }
}

// ---------------------------------------------------------------------------
// Main kernel: NO LDS, NO barrier. All weights read with wave-uniform indices
// -> compiler scalarizes to s_load (constant cache), dual-issues with VALU.
// Thread = (l, channel-quad): tid>>2 = l offset (32), tid&3 = c-quad (4).
// Block = 128 threads, grid = 16 b x 128 l-tiles = 2048 blocks.
// ---------------------------------------------------------------------------
template <bool USE_XT>
__global__ __launch_bounds__(128, 6) void deform_conv_kernel(
    const float* __restrict__ x,    // (B,1,L,C)
    const float* __restrict__ xT,   // (B,C,L) or nullptr
    const float* __restrict__ p_w, const float* __restrict__ p_b,
    const float* __restrict__ m_w, const float* __restrict__ m_b,
    const float* __restrict__ c_w, const float* __restrict__ c_b,
    float* __restrict__ out)        // (B,64,L,C)
{
    const int tid   = threadIdx.x;
    const int b     = blockIdx.x >> 7;   // 16 batches
    const int ltile = blockIdx.x & 127;  // 128 tiles of 32 positions
    const int l     = ltile * 32 + (tid >> 2);
    const int c0    = (tid & 3) * 4;     // channel quad

    const float* xb = x + (size_t)b * (LL * CC);

    // 3-tap conv inputs (zero pad at boundaries); coalesced float4 loads
    float s_m1[4] = {0.f, 0.f, 0.f, 0.f};
    float s_p1[4] = {0.f, 0.f, 0.f, 0.f};
    float s_0[4];
    {
        float4 v0 = *(const float4*)(xb + l * CC + c0);
        s_0[0] = v0.x; s_0[1] = v0.y; s_0[2] = v0.z; s_0[3] = v0.w;
        if (l > 0) {
            float4 vm = *(const float4*)(xb + (l - 1) * CC + c0);
            s_m1[0] = vm.x; s_m1[1] = vm.y; s_m1[2] = vm.z; s_m1[3] = vm.w;
        }
        if (l < LL - 1) {
            float4 vp = *(const float4*)(xb + (l + 1) * CC + c0);
            s_p1[0] = vp.x; s_p1[1] = vp.y; s_p1[2] = vp.z; s_p1[3] = vp.w;
        }
    }

    // x_off[c][k]: bilinear-gathered, masked samples.
    // p_w/p_b/m_w/m_b reads: k is a compile-time constant after unroll ->
    // uniform address -> s_load, hoisted.
    float xoff[4][KS];
    const float pl = (float)(l + 1);
    const float* xt0 = USE_XT ? (xT + (size_t)(b * CC + c0) * LL) : nullptr;
    #pragma unroll
    for (int k = 0; k < KS; ++k) {
        const float pw0 = p_w[k * 3 + 0], pw1 = p_w[k * 3 + 1],
                    pw2 = p_w[k * 3 + 2], pbk = p_b[k];
        const float mw0 = m_w[k * 3 + 0], mw1 = m_w[k * 3 + 1],
                    mw2 = m_w[k * 3 + 2], mbk = m_b[k];
        const float pn = (float)(k - 3);
        #pragma unroll
        for (int c = 0; c < 4; ++c) {
            float off  = pbk + pw0 * s_m1[c] + pw1 * s_0[c] + pw2 * s_p1[c];
            float mact = mbk + mw0 * s_m1[c] + mw1 * s_0[c] + mw2 * s_p1[c];
            float mm   = 1.f / (1.f + __expf(-mact));   // sigmoid

            float p    = pl + pn + off;
            float qltf = fminf(fmaxf(floorf(p), 0.f), (float)(LL - 1));
            float qrbf = fminf(qltf + 1.f, (float)(LL - 1));
            float pc   = fminf(fmaxf(p, 0.f), (float)(LL - 1));
            float glt  = 1.f + (qltf - pc);
            float grb  = 1.f - (qrbf - pc);

            float xlt, xrb;
            if (USE_XT) {
                // Contiguous along l: neighbors are adjacent floats.
                // Load at min(ilt, LL-2); covers the ilt==LL-1 clamp case
                // (there q_lt==q_rb==LL-1 -> both samples are x[LL-1]).
                int iload = (int)fminf(qltf, (float)(LL - 2));
                const float* pr = xt0 + (size_t)c * LL + iload;
                float va = pr[0];
                float vb = pr[1];
                xlt = (qltf >= (float)(LL - 1)) ? vb : va;
                xrb = vb;
            } else {
                int ilt = (int)qltf;
                int irb = (int)qrbf;
                xlt = xb[ilt * CC + c0 + c];
                xrb = xb[irb * CC + c0 + c];
            }
            xoff[c][k] = (glt * xlt + grb * xrb) * mm;
        }
    }

    // 7 -> 64 output-channel dot. Weights via uniform (scalar) loads.
    // Plain float4 stores (testing store path vs nontemporal).
    float* outp = out + ((size_t)(b * OUTC) * LL + l) * CC + c0;
    #pragma unroll 4
    for (int o = 0; o < OUTC; ++o) {
        const float* cw = c_w + o * 7;   // uniform -> s_load_dwordx4/x2/x1
        const float w0 = cw[0], w1 = cw[1], w2 = cw[2], w3 = cw[3],
                    w4 = cw[4], w5 = cw[5], w6 = cw[6];
        const float bias = c_b[o];
        vfloat4 res;
        #pragma unroll
        for (int c = 0; c < 4; ++c) {
            float a = bias;
            a += w0 * xoff[c][0];
            a += w1 * xoff[c][1];
            a += w2 * xoff[c][2];
            a += w3 * xoff[c][3];
            a += w4 * xoff[c][4];
            a += w5 * xoff[c][5];
            a += w6 * xoff[c][6];
            res[c] = a;
        }
        *(vfloat4*)(outp + (size_t)o * (LL * CC)) = res;
    }
}

extern "C" void kernel_launch(void* const* d_in, const int* in_sizes, int n_in,
                              void* d_out, int out_size, void* d_ws, size_t ws_size,
                              hipStream_t stream) {
    const float* x   = (const float*)d_in[0];
    const float* p_w = (const float*)d_in[1];
    const float* p_b = (const float*)d_in[2];
    const float* m_w = (const float*)d_in[3];
    const float* m_b = (const float*)d_in[4];
    const float* c_w = (const float*)d_in[5];
    const float* c_b = (const float*)d_in[6];
    float* out = (float*)d_out;

    const size_t xt_bytes = (size_t)BB * CC * LL * sizeof(float);  // 4 MB
    if (d_ws != nullptr && ws_size >= xt_bytes) {
        float* xT = (float*)d_ws;
        transpose_kernel<<<dim3(BB * 64), dim3(256), 0, stream>>>(x, xT);
        deform_conv_kernel<true><<<dim3(BB * 128), dim3(128), 0, stream>>>(
            x, xT, p_w, p_b, m_w, m_b, c_w, c_b, out);
    } else {
        deform_conv_kernel<false><<<dim3(BB * 128), dim3(128), 0, stream>>>(
            x, nullptr, p_w, p_b, m_w, m_b, c_w, c_b, out);
    }
}